// Round 8
// baseline (11.895 us; speedup 1.0000x reference)
//
#include <hip/hip_runtime.h>
#include <math.h>

#define B_SZ 256
#define U_SZ 4096
#define V_SZ 80
#define H_SZ 1024
#define K_SZ 10

// d_out layout (floats, concatenated in return order):
//   [0, B*V)                       w            (256*80   = 20480)
//   [B*V, B*V + B*K)               new_kappa    (256*10   = 2560)
//   [B*V + B*K, ... + B*(U+1))     phi_term     (256*4097 = 1048832)
#define OUT_W_OFF      0
#define OUT_NK_OFF     (B_SZ * V_SZ)
#define OUT_PT_OFF     (B_SZ * V_SZ + B_SZ * K_SZ)

// One block (1024 threads = 16 waves) per batch. TWO barriers.
//   entry:  warm c rows [0,102) (asm-sunk), x/bias/kappa -> regs
//   pre-A:  lin = x @ W.T (16 waves, float4)
//   A ----  (lin_s ready; entry vmem drained)
//   per-wave: lanes 0-9 compute alpha/beta/nk/cut (3-expf depth), shfl
//             broadcast to registers; analytic cutoff (terms < e^-60 beyond)
//   per-lane: phi(u) for u = wave + 16*lane (u < 1024 >> ucut); pt[0..ucut]
//   per-wave: w partial over u = wave+16*i — phi via __shfl from lane i,
//             c direct from global (L2-warm); partial -> wpart[wave][v]
//   E ----  (LDS-only)
//   threads 0-79: reduce 16 partials, store w
//   deferred zero-fill pt[(ucut,U]] (nontemporal, retires at endpgm)
__global__ __launch_bounds__(1024) void fused_softwindow(
        const float* __restrict__ x,
        const float* __restrict__ c,
        const float* __restrict__ kappa,
        const float* __restrict__ W,
        const float* __restrict__ bias,
        const int*   __restrict__ lens,
        float* __restrict__ out) {
    __shared__ float lin_s[32];
    __shared__ float wpart[16][V_SZ];

    const int b    = blockIdx.x;
    const int tid  = threadIdx.x;
    const int wave = tid >> 6;
    const int lane = tid & 63;
    const int len  = lens[b];

    const float*  cb  = c + (size_t)b * U_SZ * V_SZ;
    const float4* cb4 = (const float4*)cb;

    // entry: warm c rows [0, 102) into L1/L2 (2048 float4 = 32 KB)
    float4 cw0 = cb4[tid];
    float4 cw1 = cb4[tid + 1024];

    // entry: per-lane param loads (lanes 0-9 of EVERY wave; tiny, L2-hit)
    float bsa = 0.f, bsb = 0.f, bsk = 0.f, kap = 0.f;
    if (lane < K_SZ) {
        bsa = bias[lane];
        bsb = bias[K_SZ + lane];
        bsk = bias[2 * K_SZ + lane];
        kap = kappa[b * K_SZ + lane];
    }

    // entry: x per-lane slice (reused across k rows)
    const float4* xb4 = (const float4*)(x + (size_t)b * H_SZ);
    float4 xv[4];
    #pragma unroll
    for (int j = 0; j < 4; ++j) xv[j] = xb4[lane + 64 * j];

    // phase 1: lin = x @ W.T
    for (int k = wave; k < 3 * K_SZ; k += 16) {
        const float4* Wk4 = (const float4*)(W + (size_t)k * H_SZ);
        float p = 0.f;
        #pragma unroll
        for (int j = 0; j < 4; ++j) {
            float4 wv = Wk4[lane + 64 * j];
            p += wv.x * xv[j].x + wv.y * xv[j].y +
                 wv.z * xv[j].z + wv.w * xv[j].w;
        }
        #pragma unroll
        for (int off = 32; off > 0; off >>= 1) p += __shfl_down(p, off);
        if (lane == 0) lin_s[k] = p;
    }

    // keep the c-warm loads live (prevent DCE); they drain at A
    asm volatile("" :: "v"(cw0.x), "v"(cw0.y), "v"(cw0.z), "v"(cw0.w),
                       "v"(cw1.x), "v"(cw1.y), "v"(cw1.z), "v"(cw1.w));

    __syncthreads();  // A: lin_s ready

    // per-wave scalars: lanes 0-9 compute, then shfl-broadcast
    float av = 0.f, nbv = 0.f, nkv = 0.f, cutv = 0.f;
    if (lane < K_SZ) {
        float ah = lin_s[lane]            + bsa;
        float bh = lin_s[K_SZ + lane]     + bsb;
        float kh = lin_s[2 * K_SZ + lane] + bsk;
        av  = expf(ah);
        float bt = expf(bh);
        nkv = kap + expf(kh - 3.9f);
        nbv = -bt;
        // term_k(u) = exp(ah - bt*(nk-u)^2) < e^-60 beyond this u:
        cutv = nkv + sqrtf((60.f + fmaxf(ah, 0.f)) / bt);
        if (wave == 0) out[OUT_NK_OFF + b * K_SZ + lane] = nkv;
    }
    float cut = cutv;
    #pragma unroll
    for (int off = 8; off > 0; off >>= 1)
        cut = fmaxf(cut, __shfl_xor(cut, off));
    cut = __shfl(cut, 0);
    int ucut = (int)cut + 1;
    if (ucut > U_SZ) ucut = U_SZ;

    float a_[K_SZ], nb_[K_SZ], nk_[K_SZ];
    #pragma unroll
    for (int k = 0; k < K_SZ; ++k) {
        a_[k]  = __shfl(av,  k);
        nb_[k] = __shfl(nbv, k);
        nk_[k] = __shfl(nkv, k);
    }

    // per-lane phi: u = wave + 16*lane  (u in [0,1024))
    const int u = wave + 16 * lane;
    float s = 0.f;
    {
        const float fu = (float)u;
        #pragma unroll
        for (int k = 0; k < K_SZ; ++k) {
            float d = nk_[k] - fu;
            s += a_[k] * expf(nb_[k] * d * d);
        }
    }
    float* pt = out + OUT_PT_OFF + (size_t)b * (U_SZ + 1);
    if (u <= ucut) pt[u] = s;
    const float phiu = (u < len) ? s : 0.f;

    // pathological fallback (ucut >= 1024; never with this data)
    for (int uu = 1024 + tid; uu <= ucut; uu += 1024) {
        const float fu = (float)uu;
        float s2 = 0.f;
        #pragma unroll
        for (int k = 0; k < K_SZ; ++k) {
            float d = nk_[k] - fu;
            s2 += a_[k] * expf(nb_[k] * d * d);
        }
        pt[uu] = s2;
    }

    // per-wave w partial: u = wave + 16*i, phi via shfl, c from global
    const int ulim   = min(len, ucut + 1);
    const int ulim_c = min(ulim, 1024);
    float acc0 = 0.f, acc1 = 0.f;
    const int nIt = (ulim_c > wave) ? (ulim_c - wave + 15) >> 4 : 0;
    for (int i = 0; i < nIt; ++i) {
        const int ui = wave + 16 * i;
        const float p = __shfl(phiu, i);
        acc0 += p * cb[(size_t)ui * V_SZ + lane];
        if (lane < V_SZ - 64)
            acc1 += p * cb[(size_t)ui * V_SZ + 64 + lane];
    }
    // pathological fallback (ulim > 1024; never with this data)
    for (int uu = 1024; uu < ulim; ++uu) {
        const float fu = (float)uu;
        float s2 = 0.f;
        #pragma unroll
        for (int k = 0; k < K_SZ; ++k) {
            float d = nk_[k] - fu;
            s2 += a_[k] * expf(nb_[k] * d * d);
        }
        acc0 += s2 * cb[(size_t)uu * V_SZ + lane];
        if (lane < V_SZ - 64)
            acc1 += s2 * cb[(size_t)uu * V_SZ + 64 + lane];
    }
    wpart[wave][lane] = acc0;
    if (lane < V_SZ - 64) wpart[wave][64 + lane] = acc1;

    __syncthreads();  // E: wpart ready (LDS-only dependency)

    if (tid < V_SZ) {
        float sum = 0.f;
        #pragma unroll
        for (int r = 0; r < 16; ++r) sum += wpart[r][tid];
        out[OUT_W_OFF + b * V_SZ + tid] = sum;
    }

    // deferred bulk zero-fill pt[(ucut, U]] — never drained by a barrier;
    // nontemporal to avoid evicting c/W from L2.
    #pragma unroll
    for (int j = 0; j < 4; ++j) {
        int uz = ucut + 1 + tid + 1024 * j;
        if (uz <= U_SZ) __builtin_nontemporal_store(0.f, &pt[uz]);
    }
}

extern "C" void kernel_launch(void* const* d_in, const int* in_sizes, int n_in,
                              void* d_out, int out_size, void* d_ws, size_t ws_size,
                              hipStream_t stream) {
    const float* x     = (const float*)d_in[0];
    const float* c     = (const float*)d_in[1];
    const float* kappa = (const float*)d_in[2];
    const float* W     = (const float*)d_in[3];
    const float* bias  = (const float*)d_in[4];
    const int*   lens  = (const int*)d_in[5];
    float* out = (float*)d_out;

    fused_softwindow<<<B_SZ, 1024, 0, stream>>>(x, c, kappa, W, bias, lens, out);
}